// Round 4
// baseline (288.353 us; speedup 1.0000x reference)
//
#include <hip/hip_runtime.h>
#include <stdint.h>

// ---------------- JAX threefry2x32 (partitionable mode) ----------------
__host__ __device__ inline void tf2x32(uint32_t k0, uint32_t k1,
                                       uint32_t x0, uint32_t x1,
                                       uint32_t& o0, uint32_t& o1) {
  const uint32_t ks2 = k0 ^ k1 ^ 0x1BD11BDAu;
  x0 += k0; x1 += k1;
#define TFR(r) { x0 += x1; x1 = (x1 << (r)) | (x1 >> (32 - (r))); x1 ^= x0; }
  TFR(13) TFR(15) TFR(26) TFR(6)
  x0 += k1;  x1 += ks2 + 1u;
  TFR(17) TFR(29) TFR(16) TFR(24)
  x0 += ks2; x1 += k0 + 2u;
  TFR(13) TFR(15) TFR(26) TFR(6)
  x0 += k0;  x1 += k1 + 3u;
  TFR(17) TFR(29) TFR(16) TFR(24)
  x0 += k1;  x1 += ks2 + 4u;
  TFR(13) TFR(15) TFR(26) TFR(6)
  x0 += ks2; x1 += k0 + 5u;
#undef TFR
  o0 = x0; o1 = x1;
}

__host__ __device__ inline uint32_t bits32(uint32_t k0, uint32_t k1, uint32_t idx) {
  uint32_t a, b;
  tf2x32(k0, k1, 0u, idx, a, b);
  return a ^ b;
}

// keep-edge iff uniform >= 0.5 iff bit31 of bits set (floor(0.5+u) == 1)
__device__ inline bool edge_kept(uint32_t k0, uint32_t k1, uint32_t e) {
  return (bits32(k0, k1, e) >> 31) != 0u;
}

__device__ inline float bf_lo(uint32_t u) { return __uint_as_float(u << 16); }
__device__ inline float bf_hi(uint32_t u) { return __uint_as_float(u & 0xffff0000u); }
__device__ inline uint32_t bf_pack(float a, float b) {
  uint32_t lo = (__float_as_uint(a) + 0x8000u) >> 16;
  uint32_t hi = (__float_as_uint(b) + 0x8000u) & 0xffff0000u;
  return hi | lo;
}

__device__ inline void fma8_f32(float a[8], float v, const float4& x0, const float4& x1) {
  a[0] = fmaf(v, x0.x, a[0]); a[1] = fmaf(v, x0.y, a[1]);
  a[2] = fmaf(v, x0.z, a[2]); a[3] = fmaf(v, x0.w, a[3]);
  a[4] = fmaf(v, x1.x, a[4]); a[5] = fmaf(v, x1.y, a[5]);
  a[6] = fmaf(v, x1.z, a[6]); a[7] = fmaf(v, x1.w, a[7]);
}
__device__ inline void fma8_bf(float a[8], float v, const uint4& u) {
  a[0] = fmaf(v, bf_lo(u.x), a[0]); a[1] = fmaf(v, bf_hi(u.x), a[1]);
  a[2] = fmaf(v, bf_lo(u.y), a[2]); a[3] = fmaf(v, bf_hi(u.y), a[3]);
  a[4] = fmaf(v, bf_lo(u.z), a[4]); a[5] = fmaf(v, bf_hi(u.z), a[5]);
  a[6] = fmaf(v, bf_lo(u.w), a[6]); a[7] = fmaf(v, bf_hi(u.w), a[7]);
}

// ---------------- CSR build ----------------
__global__ void k_count(const int* __restrict__ rows, int nnz, int* __restrict__ cnt,
                        uint32_t ke0, uint32_t ke1) {
  int e = blockIdx.x * 256 + threadIdx.x;
  if (e >= nnz) return;
  if (edge_kept(ke0, ke1, (uint32_t)e)) atomicAdd(&cnt[rows[e]], 1);
}

__global__ void k_blocksum(const int* __restrict__ cnt, int n, int* __restrict__ bsum) {
  __shared__ int s[256];
  int i = blockIdx.x * 256 + threadIdx.x;
  s[threadIdx.x] = (i < n) ? cnt[i] : 0;
  __syncthreads();
  for (int off = 128; off > 0; off >>= 1) {
    if (threadIdx.x < off) s[threadIdx.x] += s[threadIdx.x + off];
    __syncthreads();
  }
  if (threadIdx.x == 0) bsum[blockIdx.x] = s[0];
}

// single block, 1024 threads, scans up to 2048 block sums -> exclusive prefix
__global__ void k_scanb(const int* __restrict__ bsum, int nb, int* __restrict__ bpref) {
  __shared__ int a[2048], b[2048];
  int t = threadIdx.x;
  for (int i = t; i < 2048; i += 1024) a[i] = (i < nb) ? bsum[i] : 0;
  __syncthreads();
  int* cur = a; int* nxt = b;
  for (int off = 1; off < 2048; off <<= 1) {
    for (int i = t; i < 2048; i += 1024)
      nxt[i] = cur[i] + (i >= off ? cur[i - off] : 0);
    __syncthreads();
    int* tmp = cur; cur = nxt; nxt = tmp;
  }
  for (int i = t; i <= nb; i += 1024)
    bpref[i] = (i == 0) ? 0 : cur[i - 1];
}

__global__ void k_scan_write(const int* __restrict__ cnt, int n, const int* __restrict__ bpref,
                             int* __restrict__ row_ptr, int* __restrict__ nextc) {
  __shared__ int a[256], b[256];
  int t = threadIdx.x;
  int i = blockIdx.x * 256 + t;
  int v = (i < n) ? cnt[i] : 0;
  a[t] = v;
  __syncthreads();
  int* cur = a; int* nxt = b;
  for (int off = 1; off < 256; off <<= 1) {
    nxt[t] = cur[t] + (t >= off ? cur[t - off] : 0);
    __syncthreads();
    int* tmp = cur; cur = nxt; nxt = tmp;
  }
  int incl = cur[t] + bpref[blockIdx.x];
  int excl = incl - v;
  if (i < n) { row_ptr[i] = excl; nextc[i] = excl; }
  if (i == n - 1) row_ptr[n] = incl;
}

__global__ void k_scatter(const float* __restrict__ avals, const int* __restrict__ rows,
                          const int* __restrict__ cols, int nnz, int* __restrict__ nextc,
                          int2* __restrict__ slot, uint32_t ke0, uint32_t ke1) {
  int e = blockIdx.x * 256 + threadIdx.x;
  if (e >= nnz) return;
  if (!edge_kept(ke0, ke1, (uint32_t)e)) return;
  int r = rows[e];
  int k = atomicAdd(&nextc[r], 1);
  slot[k] = make_int2(cols[e], __float_as_int(avals[e] * 2.0f)); // *keep*1/(1-0.5)
}

// ---------------- frontier marking + compaction ----------------
__global__ void k_mark_batch(const int* __restrict__ users, const int* __restrict__ items,
                             int batch, int nu, uint8_t* fB, uint8_t* f1, uint8_t* f2) {
  int i = blockIdx.x * 256 + threadIdx.x;
  if (i >= 2 * batch) return;
  int r = (i < batch) ? users[i] : nu + items[i - batch];
  fB[r] = 1; f1[r] = 1; f2[r] = 1;
}

__global__ void k_mark_neighbors(const uint8_t* __restrict__ fin,
                                 const int* __restrict__ row_ptr,
                                 const int2* __restrict__ slot, int n,
                                 uint8_t* __restrict__ fout) {
  int r = blockIdx.x * 256 + threadIdx.x;
  if (r >= n) return;
  if (!fin[r]) return;
  int s = row_ptr[r], e = row_ptr[r + 1];
  for (int k = s; k < e; ++k) fout[slot[k].x] = 1;
}

// dense list of flagged rows (order irrelevant; per-row output is exact)
__global__ void k_compact(const uint8_t* __restrict__ flag, int n,
                          int* __restrict__ list, int* __restrict__ cnt) {
  int r = blockIdx.x * 256 + threadIdx.x;
  if (r >= n) return;
  if (!flag[r]) return;
  list[atomicAdd(cnt, 1)] = r;
}

// -------- SPMM: 8 lanes per row (lane owns 8 dims), 8 rows per wave --------
// X buffers are bf16x2-packed (uint32, 32 words per row).
template <int FIRST>
__global__ __launch_bounds__(256) void k_spmm(
    const int* __restrict__ row_ptr, const int2* __restrict__ slot,
    const uint32_t* __restrict__ xin, const float* __restrict__ uemb,
    const float* __restrict__ iemb, uint32_t* __restrict__ xout,
    const int* __restrict__ rowlist, const int* __restrict__ nrows_p, int nu) {
  int nrows = *nrows_p;
  int i = blockIdx.x * 32 + (threadIdx.x >> 3);
  if (i >= nrows) return;
  int r = rowlist[i];
  int j = threadIdx.x & 7;
  int s = row_ptr[r], e = row_ptr[r + 1];
  float a[8] = {0, 0, 0, 0, 0, 0, 0, 0};
  for (int k = s; k < e; k += 2) {
    int2 s0 = slot[k];
    bool has1 = (k + 1 < e);
    int2 s1 = slot[has1 ? k + 1 : k];
    float v0 = __int_as_float(s0.y);
    float v1 = has1 ? __int_as_float(s1.y) : 0.0f;
    if (FIRST) {
      const float* p0 = (s0.x < nu) ? uemb + (size_t)s0.x * 64
                                    : iemb + (size_t)(s0.x - nu) * 64;
      const float* p1 = (s1.x < nu) ? uemb + (size_t)s1.x * 64
                                    : iemb + (size_t)(s1.x - nu) * 64;
      float4 xa0 = *(const float4*)(p0 + 8 * j);
      float4 xb0 = *(const float4*)(p0 + 8 * j + 4);
      float4 xa1 = *(const float4*)(p1 + 8 * j);
      float4 xb1 = *(const float4*)(p1 + 8 * j + 4);
      fma8_f32(a, v0, xa0, xb0);
      fma8_f32(a, v1, xa1, xb1);
    } else {
      uint4 u0 = *(const uint4*)(xin + (size_t)s0.x * 32 + 4 * j);
      uint4 u1 = *(const uint4*)(xin + (size_t)s1.x * 32 + 4 * j);
      fma8_bf(a, v0, u0);
      fma8_bf(a, v1, u1);
    }
  }
  uint4 o;
  o.x = bf_pack(a[0], a[1]); o.y = bf_pack(a[2], a[3]);
  o.z = bf_pack(a[4], a[5]); o.w = bf_pack(a[6], a[7]);
  *(uint4*)(xout + (size_t)r * 32 + 4 * j) = o;
}

// ---- layer-3 SPMM fused into the batch gather: only 2B rows needed ----
__global__ __launch_bounds__(256) void k_spmm_gather(
    const int* __restrict__ row_ptr, const int2* __restrict__ slot,
    const uint32_t* __restrict__ xin, const int* __restrict__ users,
    const int* __restrict__ items, float* __restrict__ out,
    int batch, int nu) {
  int b = blockIdx.x * 32 + (threadIdx.x >> 3);
  if (b >= 2 * batch) return;
  int j = threadIdx.x & 7;
  size_t H = (size_t)batch * 64;
  int r; size_t dst;
  if (b < batch) {
    r = users[b];
    dst = (size_t)b * 64;
  } else {
    int bi = b - batch;
    r = nu + items[bi];
    dst = 2 * H + (size_t)bi * 64;
  }
  int s = row_ptr[r], e = row_ptr[r + 1];
  float a[8] = {0, 0, 0, 0, 0, 0, 0, 0};
  for (int k = s; k < e; k += 2) {
    int2 s0 = slot[k];
    bool has1 = (k + 1 < e);
    int2 s1 = slot[has1 ? k + 1 : k];
    float v0 = __int_as_float(s0.y);
    float v1 = has1 ? __int_as_float(s1.y) : 0.0f;
    uint4 u0 = *(const uint4*)(xin + (size_t)s0.x * 32 + 4 * j);
    uint4 u1 = *(const uint4*)(xin + (size_t)s1.x * 32 + 4 * j);
    fma8_bf(a, v0, u0);
    fma8_bf(a, v1, u1);
  }
  float* o = out + dst + 8 * j;
  float4 t0 = *(float4*)o;
  float4 t1 = *(float4*)(o + 4);
  t0.x += a[0]; t0.y += a[1]; t0.z += a[2]; t0.w += a[3];
  t1.x += a[4]; t1.y += a[5]; t1.z += a[6]; t1.w += a[7];
  *(float4*)o = t0;
  *(float4*)(o + 4) = t1;
}

// ---------------- batch gather, accumulated into d_out ----------------
// out layout: [u_online | u_target | i_online | i_target], H = B*64 each.
template <int INIT>
__global__ void k_gather(const uint32_t* __restrict__ x, const float* __restrict__ uemb,
                         const float* __restrict__ iemb, const int* __restrict__ users,
                         const int* __restrict__ items, float* __restrict__ out,
                         int batch, int nu) {
  int b = blockIdx.x * 32 + (threadIdx.x >> 3);
  if (b >= 2 * batch) return;
  int j = threadIdx.x & 7;
  size_t H = (size_t)batch * 64;
  int row; size_t dst; bool isu = b < batch;
  if (isu) {
    row = users[b];
    dst = (size_t)b * 64 + 8 * j;
  } else {
    int bi = b - batch;
    row = items[bi];
    dst = 2 * H + (size_t)bi * 64 + 8 * j;
  }
  if (INIT) {
    const float* p = (isu ? uemb + (size_t)row * 64 : iemb + (size_t)row * 64) + 8 * j;
    *(float4*)(out + dst) = *(const float4*)p;
    *(float4*)(out + dst + 4) = *(const float4*)(p + 4);
  } else {
    int xr = isu ? row : nu + row;
    uint4 u = *(const uint4*)(x + (size_t)xr * 32 + 4 * j);
    float* o = out + dst;
    float4 t0 = *(float4*)o;
    float4 t1 = *(float4*)(o + 4);
    t0.x += bf_lo(u.x); t0.y += bf_hi(u.x); t0.z += bf_lo(u.y); t0.w += bf_hi(u.y);
    t1.x += bf_lo(u.z); t1.y += bf_hi(u.z); t1.z += bf_lo(u.w); t1.w += bf_hi(u.w);
    *(float4*)o = t0;
    *(float4*)(o + 4) = t1;
  }
}

// ---------------- finalize: /4, target dropout masks ----------------
__global__ void k_finalize(float* __restrict__ out, int batch,
                           uint32_t ku0, uint32_t ku1, uint32_t ki0, uint32_t ki1) {
  int j = blockIdx.x * 256 + threadIdx.x;
  int H = batch * 64;
  if (j >= 2 * H) return;
  bool is_u = j < H;
  int f = is_u ? j : j - H;
  size_t online = is_u ? (size_t)f : (size_t)2 * H + f;
  uint32_t k0 = is_u ? ku0 : ki0;
  uint32_t k1 = is_u ? ku1 : ki1;
  float o = out[online] * 0.25f;                       // acc / (N_LAYERS+1), exact
  bool present = (bits32(k0, k1, (uint32_t)f) >> 31) == 0u;  // bernoulli(0.5)
  out[online] = o;
  out[online + H] = present ? o * 2.0f : 0.0f;         // t / (1-0.5), exact
}

extern "C" void kernel_launch(void* const* d_in, const int* in_sizes, int n_in,
                              void* d_out, int out_size, void* d_ws, size_t ws_size,
                              hipStream_t stream) {
  const float* uemb  = (const float*)d_in[0];
  const float* iemb  = (const float*)d_in[1];
  const float* avals = (const float*)d_in[2];
  const int*   rows  = (const int*)d_in[3];
  const int*   cols  = (const int*)d_in[4];
  const int*   users = (const int*)d_in[5];
  const int*   items = (const int*)d_in[6];
  const int DIM = 64;
  const int NU = in_sizes[0] / DIM;
  const int NI = in_sizes[1] / DIM;
  const int NNZ = in_sizes[2];
  const int B = in_sizes[5];
  const int NN = NU + NI;
  float* out = (float*)d_out;
  (void)n_in; (void)out_size; (void)ws_size;

  // derived subkeys: split(key(1234), 3) fold-like = threefry(key, (0, i))
  uint32_t ke0, ke1, ku0, ku1, ki0, ki1;
  tf2x32(0u, 1234u, 0u, 0u, ke0, ke1);
  tf2x32(0u, 1234u, 0u, 1u, ku0, ku1);
  tf2x32(0u, 1234u, 0u, 2u, ki0, ki1);

  // workspace carve
  char* p = (char*)d_ws;
  auto carve = [&](size_t bytes) {
    char* r = p;
    p += (bytes + 255) & ~(size_t)255;
    return (void*)r;
  };
  uint32_t* X0    = (uint32_t*)carve((size_t)NN * 32 * 4);  // bf16x2 rows
  uint32_t* X1    = (uint32_t*)carve((size_t)NN * 32 * 4);
  int2*  slot     = (int2*)carve((size_t)NNZ * 8);
  int*   cnt      = (int*)carve((size_t)NN * 4);
  int*   row_ptr  = (int*)carve((size_t)(NN + 1) * 4);
  int*   nextc    = (int*)carve((size_t)NN * 4);
  uint8_t* fB     = (uint8_t*)carve((size_t)NN * 3);  // fB | f1 | f2
  uint8_t* f1     = fB + NN;
  uint8_t* f2     = fB + 2 * (size_t)NN;
  int*   list1    = (int*)carve((size_t)NN * 4);
  int*   list2    = (int*)carve((size_t)NN * 4);
  int*   rcnt     = (int*)carve(8);                   // [0]=|f1|, [1]=|f2|
  const int NB    = (NN + 255) / 256;
  int*   bsum     = (int*)carve((size_t)NB * 4);
  int*   bpref    = (int*)carve((size_t)(NB + 1) * 4);

  hipMemsetAsync(cnt, 0, (size_t)NN * 4, stream);
  hipMemsetAsync(fB, 0, (size_t)NN * 3, stream);
  hipMemsetAsync(rcnt, 0, 8, stream);

  const int gE = (NNZ + 255) / 256;
  const int gN = (NN + 255) / 256;
  k_count<<<gE, 256, 0, stream>>>(rows, NNZ, cnt, ke0, ke1);
  k_blocksum<<<NB, 256, 0, stream>>>(cnt, NN, bsum);
  k_scanb<<<1, 1024, 0, stream>>>(bsum, NB, bpref);
  k_scan_write<<<NB, 256, 0, stream>>>(cnt, NN, bpref, row_ptr, nextc);
  k_scatter<<<gE, 256, 0, stream>>>(avals, rows, cols, NNZ, nextc, slot, ke0, ke1);

  // frontier: f2 = batch ∪ N(batch); f1 = batch ∪ N(f2); compact to lists
  const int gB = (2 * B + 255) / 256;
  k_mark_batch<<<gB, 256, 0, stream>>>(users, items, B, NU, fB, f1, f2);
  k_mark_neighbors<<<gN, 256, 0, stream>>>(fB, row_ptr, slot, NN, f2);
  k_mark_neighbors<<<gN, 256, 0, stream>>>(f2, row_ptr, slot, NN, f1);
  k_compact<<<gN, 256, 0, stream>>>(f1, NN, list1, rcnt);
  k_compact<<<gN, 256, 0, stream>>>(f2, NN, list2, rcnt + 1);

  const int gG = (2 * B + 31) / 32;   // 32 rows/block (8 lanes per row)
  const int gS = (NN + 31) / 32;      // upper bound; spmm exits past rcnt

  // layer-0 contribution (the raw embeddings) into online slots
  k_gather<1><<<gG, 256, 0, stream>>>(X0, uemb, iemb, users, items, out, B, NU);

  // layer 1: X0 = A * emb (rows in list1), accumulate batch rows
  k_spmm<1><<<gS, 256, 0, stream>>>(row_ptr, slot, X1, uemb, iemb, X0, list1, rcnt, NU);
  k_gather<0><<<gG, 256, 0, stream>>>(X0, uemb, iemb, users, items, out, B, NU);
  // layer 2: X1 = A * X0 (rows in list2), accumulate batch rows
  k_spmm<0><<<gS, 256, 0, stream>>>(row_ptr, slot, X0, uemb, iemb, X1, list2, rcnt + 1, NU);
  k_gather<0><<<gG, 256, 0, stream>>>(X1, uemb, iemb, users, items, out, B, NU);
  // layer 3: only the 2B gathered rows are ever read -> fuse into gather
  k_spmm_gather<<<gG, 256, 0, stream>>>(row_ptr, slot, X1, users, items, out, B, NU);

  const int gF = (2 * B * DIM + 255) / 256;
  k_finalize<<<gF, 256, 0, stream>>>(out, B, ku0, ku1, ki0, ki1);
}